// Round 4
// baseline (522.701 us; speedup 1.0000x reference)
//
#include <hip/hip_runtime.h>

#define N_TOTAL 150000
#define DIM 128
#define NNZ_E 1500000
#define PAD 20                  // slots per destination row (Poisson(10): P(n>20)~0.2%)
#define ROW_B 160               // PAD * 8 bytes
#define OVF_CAP 4096            // overflow entries (expected ~400 edges total)

typedef unsigned long long u64;
typedef unsigned uvec16 __attribute__((ext_vector_type(16)));
typedef unsigned uvec8  __attribute__((ext_vector_type(8)));

// ---------- bf16 pack/unpack (RNE) ----------
__device__ __forceinline__ unsigned pack_bf16_bits(unsigned ua, unsigned ub) {
    ua = (ua + 0x7FFFu + ((ua >> 16) & 1u)) >> 16;
    ub = (ub + 0x7FFFu + ((ub >> 16) & 1u)) >> 16;
    return ua | (ub << 16);
}
__device__ __forceinline__ unsigned pack_bf16(float a, float b) {
    return pack_bf16_bits(__float_as_uint(a), __float_as_uint(b));
}
__device__ __forceinline__ float2 unpack_bf16(unsigned u) {
    return make_float2(__uint_as_float(u << 16), __uint_as_float(u & 0xFFFF0000u));
}
__device__ __forceinline__ float rdlane_f(float x, int l) {
    return __uint_as_float((unsigned)__builtin_amdgcn_readlane((int)__float_as_uint(x), l));
}

// ---------- one parallel scalar-load batch: 160B edge row + count ----------
__device__ __forceinline__ void sload_row20(uvec16 &a, uvec16 &b, uvec8 &c, unsigned &n,
                                            const void* tp, const void* cp) {
    asm volatile("s_load_dwordx16 %0, %4, 0x0\n\t"
                 "s_load_dwordx16 %1, %4, 0x40\n\t"
                 "s_load_dwordx8 %2, %4, 0x80\n\t"
                 "s_load_dword %3, %5, 0x0\n\t"
                 "s_waitcnt lgkmcnt(0)"
                 : "=&s"(a), "=&s"(b), "=&s"(c), "=&s"(n)
                 : "s"(tp), "s"(cp) : "memory");
}

// process 8 edges from an SGPR chunk; lim = valid count (scalar).
// Speculative slots: src clamped scalar-side, weight replaced by literal 0.0f.
__device__ __forceinline__ void chunk8(const uvec16 &m, int lim, int lane,
                                       const uint* __restrict__ srcBf,
                                       float &ax, float &ay, float &bx, float &by) {
    #pragma unroll
    for (int j = 0; j < 8; j++) {
        unsigned sx = m[2 * j] & 0x3FFFFu;
        sx = (sx < (unsigned)N_TOTAL) ? sx : 0u;
        float vv = (j < lim) ? __uint_as_float(m[2 * j + 1]) : 0.0f;
        const uint* p = srcBf + ((size_t)sx << 6);   // uniform base -> saddr load
        float2 uu = unpack_bf16(p[lane]);
        if (j & 1) { bx += vv * uu.x; by += vv * uu.y; }
        else       { ax += vv * uu.x; ay += vv * uu.y; }
    }
}
__device__ __forceinline__ void chunk4(const uvec8 &m, int lim, int lane,
                                       const uint* __restrict__ srcBf,
                                       float &ax, float &ay, float &bx, float &by) {
    #pragma unroll
    for (int j = 0; j < 4; j++) {
        unsigned sx = m[2 * j] & 0x3FFFFu;
        sx = (sx < (unsigned)N_TOTAL) ? sx : 0u;
        float vv = (j < lim) ? __uint_as_float(m[2 * j + 1]) : 0.0f;
        const uint* p = srcBf + ((size_t)sx << 6);
        float2 uu = unpack_bf16(p[lane]);
        if (j & 1) { bx += vv * uu.x; by += vv * uu.y; }
        else       { ax += vv * uu.x; ay += vv * uu.y; }
    }
}

// ---------- ego fp32 -> packed bf16 ----------
__global__ __launch_bounds__(256) void conv_bf16(const float* __restrict__ in,
                                                 uint* __restrict__ outp) {
    int i = blockIdx.x * 256 + threadIdx.x;      // exactly N*D/8 threads
    const u64* in8 = (const u64*)in;             // one u64 = 2 floats
    u64 w0 = __builtin_nontemporal_load(&in8[4 * i + 0]);
    u64 w1 = __builtin_nontemporal_load(&in8[4 * i + 1]);
    u64 w2 = __builtin_nontemporal_load(&in8[4 * i + 2]);
    u64 w3 = __builtin_nontemporal_load(&in8[4 * i + 3]);
    uint4 o;
    o.x = pack_bf16_bits((unsigned)w0, (unsigned)(w0 >> 32));
    o.y = pack_bf16_bits((unsigned)w1, (unsigned)(w1 >> 32));
    o.z = pack_bf16_bits((unsigned)w2, (unsigned)(w2 >> 32));
    o.w = pack_bf16_bits((unsigned)w3, (unsigned)(w3 >> 32));
    ((uint4*)outp)[i] = o;
}

// ---------- build padded slot table: one atomic + one 8B store per edge ----------
__global__ __launch_bounds__(256) void build_table(const int* __restrict__ dsts,
                                                   const int* __restrict__ srcs,
                                                   const float* __restrict__ vals,
                                                   int* __restrict__ cnt,
                                                   u64* __restrict__ table,
                                                   int* __restrict__ ovfCnt,
                                                   uint4* __restrict__ ovf) {
    int stride = gridDim.x * blockDim.x;
    for (int e = blockIdx.x * blockDim.x + threadIdx.x; e < NNZ_E; e += stride) {
        int d = dsts[e], s = srcs[e];
        unsigned v = __float_as_uint(vals[e]);
        int slot = atomicAdd(&cnt[d], 1);
        if (slot < PAD) {
            table[(size_t)d * PAD + slot] = (u64)(unsigned)s | ((u64)v << 32);
        } else {
            int o = atomicAdd(ovfCnt, 1);
            if (o < OVF_CAP) ovf[o] = make_uint4((unsigned)d, (unsigned)s, v, 0u);
        }
    }
}

// ---------- gather 1: fixed-address edge row, SGPR metadata, saddr gathers ----------
__global__ __launch_bounds__(256) void gather1(const uint* __restrict__ srcBf,
                                               const int* __restrict__ cnt,
                                               const u64* __restrict__ table,
                                               const int* __restrict__ ovfCnt,
                                               const uint4* __restrict__ ovf,
                                               uint* __restrict__ dstBf) {
    int lane = threadIdx.x & 63;
    int row = blockIdx.x * 4 + (threadIdx.x >> 6);   // grid covers exactly N_TOTAL
    int row_u = __builtin_amdgcn_readfirstlane(row);
    uvec16 mA, mB; uvec8 mC; unsigned nu;
    sload_row20(mA, mB, mC, nu, (const char*)table + (size_t)row_u * ROW_B, cnt + row_u);
    int n = (int)nu;
    float ax = 0.f, ay = 0.f, bx = 0.f, by = 0.f;
    chunk8(mA, n < 8 ? n : 8, lane, srcBf, ax, ay, bx, by);
    if (n > 8) {
        chunk8(mB, n - 8 < 8 ? n - 8 : 8, lane, srcBf, ax, ay, bx, by);
        if (n > 16) {
            chunk4(mC, n - 16 < 4 ? n - 16 : 4, lane, srcBf, ax, ay, bx, by);
            if (n > PAD) {                           // rare: ~0.2% of rows
                int oc = *ovfCnt; oc = oc < OVF_CAP ? oc : OVF_CAP;
                for (int i = 0; i < oc; i++) {
                    uint4 e = ovf[i];
                    if (e.x == (unsigned)row_u) {
                        float v = __uint_as_float(e.z);
                        float2 u = unpack_bf16(srcBf[(((size_t)e.y) << 6) + lane]);
                        ax += v * u.x; ay += v * u.y;
                    }
                }
            }
        }
    }
    dstBf[(size_t)row_u * 64 + lane] = pack_bf16(ax + bx, ay + by);
}

// ---------- gather 2 + LN + residual ----------
__global__ __launch_bounds__(256) void gather2_ln(const uint* __restrict__ hBf,
                                                  const int* __restrict__ cnt,
                                                  const u64* __restrict__ table,
                                                  const int* __restrict__ ovfCnt,
                                                  const uint4* __restrict__ ovf,
                                                  const uint* __restrict__ egoBf,
                                                  const float* __restrict__ gamma,
                                                  const float* __restrict__ beta,
                                                  float* __restrict__ out) {
    int lane = threadIdx.x & 63;
    int row = blockIdx.x * 4 + (threadIdx.x >> 6);
    int row_u = __builtin_amdgcn_readfirstlane(row);
    uvec16 mA, mB; uvec8 mC; unsigned nu;
    sload_row20(mA, mB, mC, nu, (const char*)table + (size_t)row_u * ROW_B, cnt + row_u);
    int n = (int)nu;
    float ax = 0.f, ay = 0.f, bx = 0.f, by = 0.f;
    chunk8(mA, n < 8 ? n : 8, lane, hBf, ax, ay, bx, by);
    if (n > 8) {
        chunk8(mB, n - 8 < 8 ? n - 8 : 8, lane, hBf, ax, ay, bx, by);
        if (n > 16) {
            chunk4(mC, n - 16 < 4 ? n - 16 : 4, lane, hBf, ax, ay, bx, by);
            if (n > PAD) {
                int oc = *ovfCnt; oc = oc < OVF_CAP ? oc : OVF_CAP;
                for (int i = 0; i < oc; i++) {
                    uint4 e = ovf[i];
                    if (e.x == (unsigned)row_u) {
                        float v = __uint_as_float(e.z);
                        float2 u = unpack_bf16(hBf[(((size_t)e.y) << 6) + lane]);
                        ax += v * u.x; ay += v * u.y;
                    }
                }
            }
        }
    }
    float2 acc = make_float2(ax + bx, ay + by);
    float s = acc.x + acc.y;
    float sq = acc.x * acc.x + acc.y * acc.y;
    #pragma unroll
    for (int o = 1; o <= 16; o <<= 1) {
        s  += __shfl_xor(s, o, 64);
        sq += __shfl_xor(sq, o, 64);
    }
    float sT  = rdlane_f(s, 0)  + rdlane_f(s, 32);
    float sqT = rdlane_f(sq, 0) + rdlane_f(sq, 32);
    float mu = sT * (1.0f / DIM);
    float var = sqT * (1.0f / DIM) - mu * mu;
    float rs = rsqrtf(var + 1e-5f);
    float2 g  = ((const float2*)gamma)[lane];
    float2 bb = ((const float2*)beta)[lane];
    unsigned egoW = __builtin_nontemporal_load(&egoBf[(size_t)row_u * 64 + lane]);
    float2 e2 = unpack_bf16(egoW);
    float2 o2;
    o2.x = (acc.x - mu) * rs * g.x + bb.x + e2.x;
    o2.y = (acc.y - mu) * rs * g.y + bb.y + e2.y;
    u64 ow = (u64)__float_as_uint(o2.x) | ((u64)__float_as_uint(o2.y) << 32);
    __builtin_nontemporal_store(ow, (u64*)out + (size_t)row_u * 64 + lane);
}

// ---------- fallback: atomic scatter path (ws too small) ----------
__device__ __forceinline__ void atomic_add_f32(float* p, float v) {
    __hip_atomic_fetch_add(p, v, __ATOMIC_RELAXED, __HIP_MEMORY_SCOPE_AGENT);
}
__global__ void scatter_kernel(const float* __restrict__ src, const float* __restrict__ vals,
                               const int* __restrict__ gidx, const int* __restrict__ sidx,
                               float* __restrict__ dst, int nnz) {
    int gid = blockIdx.x * blockDim.x + threadIdx.x;
    int e = gid >> 5, lane = gid & 31;
    if (e >= nnz) return;
    float v = vals[e];
    float4 x = ((const float4*)(src + (size_t)gidx[e] * DIM))[lane];
    float* d = dst + (size_t)sidx[e] * DIM + lane * 4;
    atomic_add_f32(d + 0, v * x.x); atomic_add_f32(d + 1, v * x.y);
    atomic_add_f32(d + 2, v * x.z); atomic_add_f32(d + 3, v * x.w);
}
__global__ void ln_residual_kernel(const float* __restrict__ h2, const float* __restrict__ ego,
                                   const float* __restrict__ gamma, const float* __restrict__ beta,
                                   float* __restrict__ out, int nrows) {
    int gid = blockIdx.x * blockDim.x + threadIdx.x;
    int row = gid >> 6, lane = gid & 63;
    if (row >= nrows) return;
    float2 x = ((const float2*)(h2 + (size_t)row * DIM))[lane];
    float s = x.x + x.y, sq = x.x * x.x + x.y * x.y;
    #pragma unroll
    for (int o = 32; o > 0; o >>= 1) { s += __shfl_xor(s, o, 64); sq += __shfl_xor(sq, o, 64); }
    float mu = s * (1.0f / DIM), var = sq * (1.0f / DIM) - mu * mu;
    float rs = rsqrtf(var + 1e-5f);
    float2 eg = ((const float2*)(ego + (size_t)row * DIM))[lane];
    float2 g = ((const float2*)gamma)[lane], b = ((const float2*)beta)[lane];
    float2 o2;
    o2.x = (x.x - mu) * rs * g.x + b.x + eg.x;
    o2.y = (x.y - mu) * rs * g.y + b.y + eg.y;
    ((float2*)(out + (size_t)row * DIM))[lane] = o2;
}

// ---------- launch ----------
extern "C" void kernel_launch(void* const* d_in, const int* in_sizes, int n_in,
                              void* d_out, int out_size, void* d_ws, size_t ws_size,
                              hipStream_t stream) {
    const float* ego   = (const float*)d_in[0];
    const float* vals  = (const float*)d_in[1];
    const float* gamma = (const float*)d_in[2];
    const float* beta  = (const float*)d_in[3];
    const int*   rows  = (const int*)d_in[4];
    const int*   cols  = (const int*)d_in[5];
    float* out = (float*)d_out;

    const size_t EGO_BF_B = (size_t)N_TOTAL * DIM * 2;               // 38.4 MB
    const size_t H_BF_B   = (size_t)N_TOTAL * DIM * 2;               // 38.4 MB
    const size_t TABLE_B  = (size_t)N_TOTAL * PAD * 8;               // 24 MB (reused pass1/pass2)
    const size_t CNT_B    = (size_t)150016 * sizeof(int);            // per-direction counters
    const size_t OVFC_B   = 256;                                     // 2 overflow counters (padded)
    const size_t OVF_B    = (size_t)OVF_CAP * 16;                    // per-direction overflow list
    const size_t REQ = EGO_BF_B + H_BF_B + TABLE_B + 2 * CNT_B + OVFC_B + 2 * OVF_B;
    const size_t H_FP32_B = (size_t)N_TOTAL * DIM * sizeof(float);   // fallback: 76.8 MB

    char* w = (char*)d_ws;
    uint* egoBf   = (uint*)w;   w += EGO_BF_B;
    uint* hBf     = (uint*)w;   w += H_BF_B;
    u64*  table   = (u64*)w;    w += TABLE_B;
    int*  cnt1    = (int*)w;    w += CNT_B;
    int*  cnt2    = (int*)w;    w += CNT_B;
    int*  ovfc    = (int*)w;    w += OVFC_B;      // ovfc[0]=dir1, ovfc[32]=dir2
    uint4* ovf1   = (uint4*)w;  w += OVF_B;
    uint4* ovf2   = (uint4*)w;  w += OVF_B;

    if (ws_size >= REQ) {
        // zero both counter arrays + overflow counters in one memset (contiguous)
        (void)hipMemsetAsync(cnt1, 0, 2 * CNT_B + OVFC_B, stream);
        conv_bf16<<<(N_TOTAL * DIM / 8) / 256, 256, 0, stream>>>(ego, egoBf);

        // pass 1: dest = col, src = row
        build_table<<<2048, 256, 0, stream>>>(cols, rows, vals, cnt1, table, ovfc, ovf1);
        int ggrid = N_TOTAL / 4;                  // 4 waves/block, 1 row/wave
        gather1<<<ggrid, 256, 0, stream>>>(egoBf, cnt1, table, ovfc, ovf1, hBf);

        // pass 2: dest = row, src = col (table region reused; stale slots weight-gated)
        build_table<<<2048, 256, 0, stream>>>(rows, cols, vals, cnt2, table, ovfc + 32, ovf2);
        gather2_ln<<<ggrid, 256, 0, stream>>>(hBf, cnt2, table, ovfc + 32, ovf2,
                                              egoBf, gamma, beta, out);
    } else {
        float* h = (float*)d_ws;            // fallback: fp32 h at ws start
        (void)hipMemsetAsync(h, 0, H_FP32_B, stream);
        (void)hipMemsetAsync(out, 0, H_FP32_B, stream);
        long total = (long)NNZ_E * 32;
        int grid = (int)((total + 255) / 256);
        scatter_kernel<<<grid, 256, 0, stream>>>(ego, vals, rows, cols, h, NNZ_E);
        scatter_kernel<<<grid, 256, 0, stream>>>(h, vals, cols, rows, out, NNZ_E);
        int lngrid = (N_TOTAL * 64 + 255) / 256;
        ln_residual_kernel<<<lngrid, 256, 0, stream>>>(out, ego, gamma, beta, out, N_TOTAL);
    }
}

// Round 5
// 432.406 us; speedup vs baseline: 1.2088x; 1.2088x over previous
//
#include <hip/hip_runtime.h>

#define N_TOTAL 150000
#define DIM 128
#define NNZ_E 1500000
#define NBUCK 256
#define DPB 586                 // dests per bucket: 256*586 = 150016 >= 150000
#define EPB2 2048               // edges per fused phase-A block (emits 2 entries each)
#define A2_BLOCKS ((NNZ_E + EPB2 - 1) / EPB2)   // 733

typedef unsigned long long u64;
typedef unsigned uvec16 __attribute__((ext_vector_type(16)));
typedef unsigned uvec2  __attribute__((ext_vector_type(2)));

// ---------- bf16 pack/unpack (RNE) ----------
__device__ __forceinline__ unsigned pack_bf16_bits(unsigned ua, unsigned ub) {
    ua = (ua + 0x7FFFu + ((ua >> 16) & 1u)) >> 16;
    ub = (ub + 0x7FFFu + ((ub >> 16) & 1u)) >> 16;
    return ua | (ub << 16);
}
__device__ __forceinline__ unsigned pack_bf16(float a, float b) {
    return pack_bf16_bits(__float_as_uint(a), __float_as_uint(b));
}
__device__ __forceinline__ float2 unpack_bf16(unsigned u) {
    return make_float2(__uint_as_float(u << 16), __uint_as_float(u & 0xFFFF0000u));
}
__device__ __forceinline__ float rdlane_f(float x, int l) {
    return __uint_as_float((unsigned)__builtin_amdgcn_readlane((int)__float_as_uint(x), l));
}

// ---------- scalar-pipe metadata loads (wave-uniform) ----------
__device__ __forceinline__ void sload_pair(uvec16 &a, uvec16 &b, const void* p) {
    asm volatile("s_load_dwordx16 %0, %2, 0x0\n\t"
                 "s_load_dwordx16 %1, %2, 0x40\n\t"
                 "s_waitcnt lgkmcnt(0)"
                 : "=&s"(a), "=&s"(b) : "s"(p) : "memory");
}
__device__ __forceinline__ void sload_be(uvec2 &r, const void* p) {
    asm volatile("s_load_dwordx2 %0, %1, 0x0\n\t"
                 "s_waitcnt lgkmcnt(0)"
                 : "=&s"(r) : "s"(p) : "memory");
}

// One edge slot, guarded by a wave-uniform scalar branch: executes VALU only
// when slot GJ is valid. No clamp/select needed inside (guard guarantees valid).
#define EDGE_M(M, J, GJ, SRCP)                                        \
    if (n > (GJ)) {                                                   \
        unsigned sx_ = (M)[2 * (J)];                                  \
        float vv_ = __uint_as_float((M)[2 * (J) + 1]);                \
        const uint* p_ = (SRCP) + ((size_t)sx_ << 6);                 \
        float2 uu_ = unpack_bf16(p_[lane]);                           \
        if ((GJ) & 1) { bx += vv_ * uu_.x; by += vv_ * uu_.y; }       \
        else          { ax += vv_ * uu_.x; ay += vv_ * uu_.y; }       \
    }

// ---------- ego fp32 -> packed bf16 (nontemporal via u64 lanes) ----------
__global__ __launch_bounds__(256) void conv_bf16(const float* __restrict__ in,
                                                 uint* __restrict__ outp) {
    int i = blockIdx.x * 256 + threadIdx.x;      // exactly N*D/8 threads
    const u64* in8 = (const u64*)in;             // one u64 = 2 floats
    u64 w0 = __builtin_nontemporal_load(&in8[4 * i + 0]);
    u64 w1 = __builtin_nontemporal_load(&in8[4 * i + 1]);
    u64 w2 = __builtin_nontemporal_load(&in8[4 * i + 2]);
    u64 w3 = __builtin_nontemporal_load(&in8[4 * i + 3]);
    uint4 o;
    o.x = pack_bf16_bits((unsigned)w0, (unsigned)(w0 >> 32));
    o.y = pack_bf16_bits((unsigned)w1, (unsigned)(w1 >> 32));
    o.z = pack_bf16_bits((unsigned)w2, (unsigned)(w2 >> 32));
    o.w = pack_bf16_bits((unsigned)w3, (unsigned)(w3 >> 32));
    ((uint4*)outp)[i] = o;
}

// ---------- coarse histogram: 2x256 buckets, LDS-aggregated ----------
__global__ __launch_bounds__(256) void coarse_hist(const int* __restrict__ rows,
                                                   const int* __restrict__ cols,
                                                   int* __restrict__ cnt1,
                                                   int* __restrict__ cnt2) {
    __shared__ int h[512];
    int t = threadIdx.x;
    h[t] = 0; h[t + 256] = 0;
    __syncthreads();
    int stride = gridDim.x * blockDim.x;
    for (int e = blockIdx.x * blockDim.x + t; e < NNZ_E; e += stride) {
        atomicAdd(&h[cols[e] / DPB], 1);          // pass-1 dest = col
        atomicAdd(&h[256 + rows[e] / DPB], 1);    // pass-2 dest = row
    }
    __syncthreads();
    if (h[t]) atomicAdd(&cnt1[t], h[t]);
    if (h[t + 256]) atomicAdd(&cnt2[t], h[t + 256]);
}

// ---------- scan 512 bucket counts -> slab bases sb[513]; zero cursors ----------
__global__ __launch_bounds__(256) void scan_buckets(const int* __restrict__ cnt,
                                                    int* __restrict__ sb,
                                                    int* __restrict__ gc) {
    __shared__ int buf[256];
    int t = threadIdx.x;
    int v = cnt[t]; buf[t] = v; __syncthreads();
    for (int o = 1; o < 256; o <<= 1) {
        int a = (t >= o) ? buf[t - o] : 0; __syncthreads();
        buf[t] += a; __syncthreads();
    }
    sb[t] = buf[t] - v;               // pass-1 region: [0, NNZ)
    __syncthreads();
    int v2 = cnt[256 + t]; buf[t] = v2; __syncthreads();
    for (int o = 1; o < 256; o <<= 1) {
        int a = (t >= o) ? buf[t - o] : 0; __syncthreads();
        buf[t] += a; __syncthreads();
    }
    sb[256 + t] = NNZ_E + buf[t] - v2;  // pass-2 region: [NNZ, 2*NNZ)
    if (t == 255) sb[512] = 2 * NNZ_E;
    gc[t] = 0; gc[256 + t] = 0;
}

// ---------- fused phase A: bin 2048 edges -> 4096 entries over 512 buckets ----------
__global__ __launch_bounds__(256) void phaseA_fused(const int* __restrict__ rows,
                                                    const int* __restrict__ cols,
                                                    const float* __restrict__ vals,
                                                    const int* __restrict__ slabBase,
                                                    int* __restrict__ gCur,
                                                    uint2* __restrict__ slab) {
    __shared__ uint2 sortedL[2 * EPB2];          // 32 KB
    __shared__ unsigned short bktL[2 * EPB2];    // 8 KB
    __shared__ int cnt[512], off[512], cur[512], gbase[512];   // 8 KB
    __shared__ int part[256];                    // 1 KB
    __shared__ int totE;
    int t = threadIdx.x;
    int base = blockIdx.x * EPB2;
    cnt[t] = 0; cnt[t + 256] = 0;
    __syncthreads();

    uint2 eA[8], eB[8];
    short bA[8], bB[8];
    #pragma unroll
    for (int j = 0; j < 8; j++) {
        int e = base + j * 256 + t;
        if (e < NNZ_E) {
            int r = rows[e], c = cols[e];
            unsigned v = __float_as_uint(vals[e]);
            int b1 = c / DPB, dl1 = c - b1 * DPB;     // pass-1 dest = col, src = row
            int b2 = r / DPB, dl2 = r - b2 * DPB;     // pass-2 dest = row, src = col
            bA[j] = (short)b1;
            eA[j].x = ((unsigned)dl1 << 18) | (unsigned)r;
            eA[j].y = v;
            bB[j] = (short)(256 + b2);
            eB[j].x = ((unsigned)dl2 << 18) | (unsigned)c;
            eB[j].y = v;
            atomicAdd(&cnt[b1], 1);
            atomicAdd(&cnt[256 + b2], 1);
        } else { bA[j] = -1; bB[j] = -1; }
    }
    __syncthreads();
    // scan 512 counts (2 per thread) -> exclusive off/cur
    int c0 = cnt[2 * t], c1 = cnt[2 * t + 1];
    int ps = c0 + c1;
    part[t] = ps; __syncthreads();
    for (int o = 1; o < 256; o <<= 1) {
        int a = (t >= o) ? part[t - o] : 0; __syncthreads();
        part[t] += a; __syncthreads();
    }
    int bs = part[t] - ps;
    off[2 * t] = bs;          cur[2 * t] = bs;
    off[2 * t + 1] = bs + c0; cur[2 * t + 1] = bs + c0;
    if (t == 255) totE = part[255];
    __syncthreads();
    // bucket-sorted scatter into LDS (both entries per edge)
    #pragma unroll
    for (int j = 0; j < 8; j++) {
        if (bA[j] >= 0) {
            int p = atomicAdd(&cur[(int)bA[j]], 1);
            sortedL[p] = eA[j]; bktL[p] = (unsigned short)bA[j];
            p = atomicAdd(&cur[(int)bB[j]], 1);
            sortedL[p] = eB[j]; bktL[p] = (unsigned short)bB[j];
        }
    }
    __syncthreads();
    // reserve global slab space, one atomic per non-empty bucket
    for (int b = t; b < 512; b += 256) {
        int n = cnt[b];
        if (n > 0) gbase[b] = atomicAdd(&gCur[b], n);
    }
    __syncthreads();
    int nE = totE;
    for (int i = t; i < nE; i += 256) {
        int b = bktL[i];
        slab[slabBase[b] + gbase[b] + (i - off[b])] = sortedL[i];
    }
}

// ---------- phase B: per-bucket exact sort + offs write + (src,val) emit ----------
__global__ __launch_bounds__(256) void phaseB(const uint2* __restrict__ slab,
                                              const int* __restrict__ slabBase,
                                              int* __restrict__ offs1,
                                              int* __restrict__ offs2,
                                              uint2* __restrict__ sorted) {
    __shared__ int cnt[DPB], sc[DPB], cur[DPB], part[256];
    int b = blockIdx.x, t = threadIdx.x;
    int sb = slabBase[b], se = slabBase[b + 1];
    int n = se - sb;
    for (int d = t; d < DPB; d += 256) cnt[d] = 0;
    __syncthreads();
    for (int i = t; i < n; i += 256)
        atomicAdd(&cnt[slab[sb + i].x >> 18], 1);
    __syncthreads();
    int d0 = t * 3;
    int c0 = (d0     < DPB) ? cnt[d0]     : 0;
    int c1 = (d0 + 1 < DPB) ? cnt[d0 + 1] : 0;
    int c2 = (d0 + 2 < DPB) ? cnt[d0 + 2] : 0;
    int ps = c0 + c1 + c2;
    part[t] = ps;
    __syncthreads();
    for (int o = 1; o < 256; o <<= 1) {
        int a = (t >= o) ? part[t - o] : 0; __syncthreads();
        part[t] += a; __syncthreads();
    }
    int bs = part[t] - ps;
    if (d0     < DPB) { sc[d0]     = bs;           cur[d0]     = bs; }
    if (d0 + 1 < DPB) { sc[d0 + 1] = bs + c0;      cur[d0 + 1] = bs + c0; }
    if (d0 + 2 < DPB) { sc[d0 + 2] = bs + c0 + c1; cur[d0 + 2] = bs + c0 + c1; }
    __syncthreads();
    int destBase = (b & 255) * DPB;
    int* offs = (b < NBUCK) ? offs1 : offs2;
    for (int d = t; d < DPB; d += 256) {
        int dd = destBase + d;
        if (dd <= N_TOTAL) offs[dd] = sb + sc[d];   // absolute index into sorted[]
    }
    for (int i = t; i < n; i += 256) {
        uint2 e = slab[sb + i];
        int dl = e.x >> 18;
        int p = atomicAdd(&cur[dl], 1);
        sorted[sb + p] = make_uint2(e.x & 0x3FFFF, e.y);
    }
}

// ---------- gather 1: SGPR metadata, exact-n scalar-branch slots ----------
__global__ __launch_bounds__(256) void gather1(const uint* __restrict__ srcBf,
                                               const int* __restrict__ offs,
                                               const uint2* __restrict__ edges,
                                               uint* __restrict__ dstBf) {
    int lane = threadIdx.x & 63;
    int row = blockIdx.x * 4 + (threadIdx.x >> 6);      // grid covers exactly N_TOTAL
    int row_u = __builtin_amdgcn_readfirstlane(row);
    uvec2 be;
    sload_be(be, offs + row_u);
    int beg = (int)be[0];
    int n = (int)be[1] - beg;
    const u64* ep = (const u64*)edges + beg;
    uvec16 mA, mB;
    sload_pair(mA, mB, ep);                             // <=128B past array end stays in ws
    float ax = 0.f, ay = 0.f, bx = 0.f, by = 0.f;
    EDGE_M(mA, 0,  0, srcBf) EDGE_M(mA, 1,  1, srcBf)
    EDGE_M(mA, 2,  2, srcBf) EDGE_M(mA, 3,  3, srcBf)
    EDGE_M(mA, 4,  4, srcBf) EDGE_M(mA, 5,  5, srcBf)
    EDGE_M(mA, 6,  6, srcBf) EDGE_M(mA, 7,  7, srcBf)
    EDGE_M(mB, 0,  8, srcBf) EDGE_M(mB, 1,  9, srcBf)
    EDGE_M(mB, 2, 10, srcBf) EDGE_M(mB, 3, 11, srcBf)
    EDGE_M(mB, 4, 12, srcBf) EDGE_M(mB, 5, 13, srcBf)
    EDGE_M(mB, 6, 14, srcBf) EDGE_M(mB, 7, 15, srcBf)
    if (n > 16) {
        uvec16 mC, mD;
        sload_pair(mC, mD, ep + 16);
        EDGE_M(mC, 0, 16, srcBf) EDGE_M(mC, 1, 17, srcBf)
        EDGE_M(mC, 2, 18, srcBf) EDGE_M(mC, 3, 19, srcBf)
        EDGE_M(mC, 4, 20, srcBf) EDGE_M(mC, 5, 21, srcBf)
        EDGE_M(mC, 6, 22, srcBf) EDGE_M(mC, 7, 23, srcBf)
        EDGE_M(mD, 0, 24, srcBf) EDGE_M(mD, 1, 25, srcBf)
        EDGE_M(mD, 2, 26, srcBf) EDGE_M(mD, 3, 27, srcBf)
        EDGE_M(mD, 4, 28, srcBf) EDGE_M(mD, 5, 29, srcBf)
        EDGE_M(mD, 6, 30, srcBf) EDGE_M(mD, 7, 31, srcBf)
        for (int k = 32; k < n; k++) {                  // statistically never
            uint2 e = edges[beg + k];
            float v = __uint_as_float(e.y);
            float2 u = unpack_bf16(srcBf[(((size_t)e.x) << 6) + lane]);
            ax += v * u.x; ay += v * u.y;
        }
    }
    dstBf[(size_t)row_u * 64 + lane] = pack_bf16(ax + bx, ay + by);
}

// ---------- gather 2 + LN + residual: SGPR metadata, exact-n slots ----------
__global__ __launch_bounds__(256) void gather2_ln(const uint* __restrict__ hBf,
                                                  const int* __restrict__ offs,
                                                  const uint2* __restrict__ edges,
                                                  const uint* __restrict__ egoBf,
                                                  const float* __restrict__ gamma,
                                                  const float* __restrict__ beta,
                                                  float* __restrict__ out) {
    int lane = threadIdx.x & 63;
    int row = blockIdx.x * 4 + (threadIdx.x >> 6);
    int row_u = __builtin_amdgcn_readfirstlane(row);
    uvec2 be;
    sload_be(be, offs + row_u);
    int beg = (int)be[0];
    int n = (int)be[1] - beg;
    const u64* ep = (const u64*)edges + beg;
    uvec16 mA, mB;
    sload_pair(mA, mB, ep);
    float ax = 0.f, ay = 0.f, bx = 0.f, by = 0.f;
    EDGE_M(mA, 0,  0, hBf) EDGE_M(mA, 1,  1, hBf)
    EDGE_M(mA, 2,  2, hBf) EDGE_M(mA, 3,  3, hBf)
    EDGE_M(mA, 4,  4, hBf) EDGE_M(mA, 5,  5, hBf)
    EDGE_M(mA, 6,  6, hBf) EDGE_M(mA, 7,  7, hBf)
    EDGE_M(mB, 0,  8, hBf) EDGE_M(mB, 1,  9, hBf)
    EDGE_M(mB, 2, 10, hBf) EDGE_M(mB, 3, 11, hBf)
    EDGE_M(mB, 4, 12, hBf) EDGE_M(mB, 5, 13, hBf)
    EDGE_M(mB, 6, 14, hBf) EDGE_M(mB, 7, 15, hBf)
    if (n > 16) {
        uvec16 mC, mD;
        sload_pair(mC, mD, ep + 16);
        EDGE_M(mC, 0, 16, hBf) EDGE_M(mC, 1, 17, hBf)
        EDGE_M(mC, 2, 18, hBf) EDGE_M(mC, 3, 19, hBf)
        EDGE_M(mC, 4, 20, hBf) EDGE_M(mC, 5, 21, hBf)
        EDGE_M(mC, 6, 22, hBf) EDGE_M(mC, 7, 23, hBf)
        EDGE_M(mD, 0, 24, hBf) EDGE_M(mD, 1, 25, hBf)
        EDGE_M(mD, 2, 26, hBf) EDGE_M(mD, 3, 27, hBf)
        EDGE_M(mD, 4, 28, hBf) EDGE_M(mD, 5, 29, hBf)
        EDGE_M(mD, 6, 30, hBf) EDGE_M(mD, 7, 31, hBf)
        for (int k = 32; k < n; k++) {
            uint2 e = edges[beg + k];
            float v = __uint_as_float(e.y);
            float2 u = unpack_bf16(hBf[(((size_t)e.x) << 6) + lane]);
            ax += v * u.x; ay += v * u.y;
        }
    }
    float2 acc = make_float2(ax + bx, ay + by);
    float s = acc.x + acc.y;
    float sq = acc.x * acc.x + acc.y * acc.y;
    #pragma unroll
    for (int o = 1; o <= 16; o <<= 1) {
        s  += __shfl_xor(s, o, 64);
        sq += __shfl_xor(sq, o, 64);
    }
    // lanes 0 and 32 hold the two half-sums -> finish with scalar readlanes
    float sT  = rdlane_f(s, 0)  + rdlane_f(s, 32);
    float sqT = rdlane_f(sq, 0) + rdlane_f(sq, 32);
    float mu = sT * (1.0f / DIM);
    float var = sqT * (1.0f / DIM) - mu * mu;
    float rs = rsqrtf(var + 1e-5f);
    float2 g  = ((const float2*)gamma)[lane];
    float2 bb = ((const float2*)beta)[lane];
    unsigned egoW = __builtin_nontemporal_load(&egoBf[(size_t)row_u * 64 + lane]);
    float2 e2 = unpack_bf16(egoW);
    float2 o2;
    o2.x = (acc.x - mu) * rs * g.x + bb.x + e2.x;
    o2.y = (acc.y - mu) * rs * g.y + bb.y + e2.y;
    u64 ow = (u64)__float_as_uint(o2.x) | ((u64)__float_as_uint(o2.y) << 32);
    __builtin_nontemporal_store(ow, (u64*)out + (size_t)row_u * 64 + lane);
}

// ---------- fallback: atomic scatter path (ws too small) ----------
__device__ __forceinline__ void atomic_add_f32(float* p, float v) {
    __hip_atomic_fetch_add(p, v, __ATOMIC_RELAXED, __HIP_MEMORY_SCOPE_AGENT);
}
__global__ void scatter_kernel(const float* __restrict__ src, const float* __restrict__ vals,
                               const int* __restrict__ gidx, const int* __restrict__ sidx,
                               float* __restrict__ dst, int nnz) {
    int gid = blockIdx.x * blockDim.x + threadIdx.x;
    int e = gid >> 5, lane = gid & 31;
    if (e >= nnz) return;
    float v = vals[e];
    float4 x = ((const float4*)(src + (size_t)gidx[e] * DIM))[lane];
    float* d = dst + (size_t)sidx[e] * DIM + lane * 4;
    atomic_add_f32(d + 0, v * x.x); atomic_add_f32(d + 1, v * x.y);
    atomic_add_f32(d + 2, v * x.z); atomic_add_f32(d + 3, v * x.w);
}
__global__ void ln_residual_kernel(const float* __restrict__ h2, const float* __restrict__ ego,
                                   const float* __restrict__ gamma, const float* __restrict__ beta,
                                   float* __restrict__ out, int nrows) {
    int gid = blockIdx.x * blockDim.x + threadIdx.x;
    int row = gid >> 6, lane = gid & 63;
    if (row >= nrows) return;
    float2 x = ((const float2*)(h2 + (size_t)row * DIM))[lane];
    float s = x.x + x.y, sq = x.x * x.x + x.y * x.y;
    #pragma unroll
    for (int o = 32; o > 0; o >>= 1) { s += __shfl_xor(s, o, 64); sq += __shfl_xor(sq, o, 64); }
    float mu = s * (1.0f / DIM), var = sq * (1.0f / DIM) - mu * mu;
    float rs = rsqrtf(var + 1e-5f);
    float2 eg = ((const float2*)(ego + (size_t)row * DIM))[lane];
    float2 g = ((const float2*)gamma)[lane], b = ((const float2*)beta)[lane];
    float2 o2;
    o2.x = (x.x - mu) * rs * g.x + b.x + eg.x;
    o2.y = (x.y - mu) * rs * g.y + b.y + eg.y;
    ((float2*)(out + (size_t)row * DIM))[lane] = o2;
}

// ---------- launch ----------
extern "C" void kernel_launch(void* const* d_in, const int* in_sizes, int n_in,
                              void* d_out, int out_size, void* d_ws, size_t ws_size,
                              hipStream_t stream) {
    const float* ego   = (const float*)d_in[0];
    const float* vals  = (const float*)d_in[1];
    const float* gamma = (const float*)d_in[2];
    const float* beta  = (const float*)d_in[3];
    const int*   rows  = (const int*)d_in[4];
    const int*   cols  = (const int*)d_in[5];
    float* out = (float*)d_out;

    const size_t EGO_BF_B = (size_t)N_TOTAL * DIM * 2;               // 38.4 MB
    const size_t SLAB_B   = (size_t)2 * NNZ_E * sizeof(uint2);       // 24 MB
    const size_t H_BF_B   = (size_t)N_TOTAL * DIM * 2;               // 38.4 MB
    const size_t REGION_B = (SLAB_B > H_BF_B) ? SLAB_B : H_BF_B;     // hBf aliases dead slab
    const size_t SORT_B   = (size_t)2 * NNZ_E * sizeof(uint2);       // 24 MB
    const size_t OFFS_B   = ((size_t)N_TOTAL + 16) * sizeof(int);    // ~0.6 MB each
    const size_t SMALL    = 16384;
    const size_t REQ = EGO_BF_B + REGION_B + SORT_B + 2 * OFFS_B + SMALL;   // ~102 MB
    const size_t H_FP32_B = (size_t)N_TOTAL * DIM * sizeof(float);   // fallback: 76.8 MB

    char* w = (char*)d_ws;
    uint* egoBf   = (uint*)w;   w += EGO_BF_B;
    char* region  = w;          w += REGION_B;
    uint2* slab   = (uint2*)region;      // live: phaseA_fused -> phaseB
    uint* hBf     = (uint*)region;       // live: gather1 -> gather2 (slab dead by then)
    uint2* sorted = (uint2*)w;  w += SORT_B;
    int* offs1    = (int*)w;    w += OFFS_B;
    int* offs2    = (int*)w;    w += OFFS_B;
    int* cntArr   = (int*)w;    w += 512 * sizeof(int);
    int* sb       = (int*)w;    w += 516 * sizeof(int);
    int* gc       = (int*)w;    w += 512 * sizeof(int);

    if (ws_size >= REQ) {
        (void)hipMemsetAsync(cntArr, 0, 512 * sizeof(int), stream);
        conv_bf16<<<(N_TOTAL * DIM / 8) / 256, 256, 0, stream>>>(ego, egoBf);
        coarse_hist<<<512, 256, 0, stream>>>(rows, cols, cntArr, cntArr + 256);
        scan_buckets<<<1, 256, 0, stream>>>(cntArr, sb, gc);
        phaseA_fused<<<A2_BLOCKS, 256, 0, stream>>>(rows, cols, vals, sb, gc, slab);
        phaseB<<<512, 256, 0, stream>>>(slab, sb, offs1, offs2, sorted);

        int ggrid = (N_TOTAL + 3) / 4;      // 4 waves/block, 1 row/wave -> 37500
        gather1<<<ggrid, 256, 0, stream>>>(egoBf, offs1, sorted, hBf);
        gather2_ln<<<ggrid, 256, 0, stream>>>(hBf, offs2, sorted, egoBf, gamma, beta, out);
    } else {
        float* h = (float*)d_ws;            // fallback: fp32 h at ws start
        (void)hipMemsetAsync(h, 0, H_FP32_B, stream);
        (void)hipMemsetAsync(out, 0, H_FP32_B, stream);
        long total = (long)NNZ_E * 32;
        int grid = (int)((total + 255) / 256);
        scatter_kernel<<<grid, 256, 0, stream>>>(ego, vals, rows, cols, h, NNZ_E);
        scatter_kernel<<<grid, 256, 0, stream>>>(h, vals, cols, rows, out, NNZ_E);
        int lngrid = (N_TOTAL * 64 + 255) / 256;
        ln_residual_kernel<<<lngrid, 256, 0, stream>>>(out, ego, gamma, beta, out, N_TOTAL);
    }
}

// Round 6
// 365.194 us; speedup vs baseline: 1.4313x; 1.1840x over previous
//
#include <hip/hip_runtime.h>

#define N_TOTAL 150000
#define DIM 128
#define NNZ_E 1500000
#define NBUCK 256
#define DPB 586                 // dests per bucket: 256*586 = 150016 >= 150000
#define EPB2 2048               // edges per fused phase-A block (emits 2 entries each)
#define A2_BLOCKS ((NNZ_E + EPB2 - 1) / EPB2)   // 733

typedef unsigned long long u64;
typedef unsigned uvec16 __attribute__((ext_vector_type(16)));
typedef unsigned uvec2  __attribute__((ext_vector_type(2)));

// ---------- bf16 pack/unpack (RNE) ----------
__device__ __forceinline__ unsigned pack_bf16_bits(unsigned ua, unsigned ub) {
    ua = (ua + 0x7FFFu + ((ua >> 16) & 1u)) >> 16;
    ub = (ub + 0x7FFFu + ((ub >> 16) & 1u)) >> 16;
    return ua | (ub << 16);
}
__device__ __forceinline__ unsigned pack_bf16(float a, float b) {
    return pack_bf16_bits(__float_as_uint(a), __float_as_uint(b));
}
__device__ __forceinline__ float2 unpack_bf16(unsigned u) {
    return make_float2(__uint_as_float(u << 16), __uint_as_float(u & 0xFFFF0000u));
}
__device__ __forceinline__ float rdlane_f(float x, int l) {
    return __uint_as_float((unsigned)__builtin_amdgcn_readlane((int)__float_as_uint(x), l));
}

// ---------- scalar-pipe metadata loads (wave-uniform) ----------
__device__ __forceinline__ void sload_pair(uvec16 &a, uvec16 &b, const void* p) {
    asm volatile("s_load_dwordx16 %0, %2, 0x0\n\t"
                 "s_load_dwordx16 %1, %2, 0x40\n\t"
                 "s_waitcnt lgkmcnt(0)"
                 : "=&s"(a), "=&s"(b) : "s"(p) : "memory");
}
__device__ __forceinline__ void sload_be(uvec2 &r, const void* p) {
    asm volatile("s_load_dwordx2 %0, %1, 0x0\n\t"
                 "s_waitcnt lgkmcnt(0)"
                 : "=&s"(r) : "s"(p) : "memory");
}

// process 8 edges from an SGPR chunk; lim = valid count (scalar).
// Speculative slots: index AND weight gated scalar-side (s_cselect) -> invalid
// slots all load row 0 (L1-hot) instead of random garbage rows. Loads stay
// branchless so the whole batch issues in parallel (round-5 lesson).
__device__ __forceinline__ void chunk8(const uvec16 &m, int lim, int lane,
                                       const uint* __restrict__ srcBf,
                                       float &ax, float &ay, float &bx, float &by) {
    #pragma unroll
    for (int j = 0; j < 8; j++) {
        unsigned sx = (j < lim) ? (m[2 * j] & 0x3FFFFu) : 0u;
        float vv = (j < lim) ? __uint_as_float(m[2 * j + 1]) : 0.0f;
        const uint* p = srcBf + ((size_t)sx << 6);   // uniform base -> saddr load
        float2 uu = unpack_bf16(p[lane]);
        if (j & 1) { bx += vv * uu.x; by += vv * uu.y; }
        else       { ax += vv * uu.x; ay += vv * uu.y; }
    }
}

// ---------- ego fp32 -> packed bf16 (nontemporal via u64 lanes) ----------
__global__ __launch_bounds__(256) void conv_bf16(const float* __restrict__ in,
                                                 uint* __restrict__ outp) {
    int i = blockIdx.x * 256 + threadIdx.x;      // exactly N*D/8 threads
    const u64* in8 = (const u64*)in;             // one u64 = 2 floats
    u64 w0 = __builtin_nontemporal_load(&in8[4 * i + 0]);
    u64 w1 = __builtin_nontemporal_load(&in8[4 * i + 1]);
    u64 w2 = __builtin_nontemporal_load(&in8[4 * i + 2]);
    u64 w3 = __builtin_nontemporal_load(&in8[4 * i + 3]);
    uint4 o;
    o.x = pack_bf16_bits((unsigned)w0, (unsigned)(w0 >> 32));
    o.y = pack_bf16_bits((unsigned)w1, (unsigned)(w1 >> 32));
    o.z = pack_bf16_bits((unsigned)w2, (unsigned)(w2 >> 32));
    o.w = pack_bf16_bits((unsigned)w3, (unsigned)(w3 >> 32));
    ((uint4*)outp)[i] = o;
}

// ---------- coarse histogram: 2x256 buckets, LDS-aggregated ----------
__global__ __launch_bounds__(256) void coarse_hist(const int* __restrict__ rows,
                                                   const int* __restrict__ cols,
                                                   int* __restrict__ cnt1,
                                                   int* __restrict__ cnt2) {
    __shared__ int h[512];
    int t = threadIdx.x;
    h[t] = 0; h[t + 256] = 0;
    __syncthreads();
    int stride = gridDim.x * blockDim.x;
    for (int e = blockIdx.x * blockDim.x + t; e < NNZ_E; e += stride) {
        atomicAdd(&h[cols[e] / DPB], 1);          // pass-1 dest = col
        atomicAdd(&h[256 + rows[e] / DPB], 1);    // pass-2 dest = row
    }
    __syncthreads();
    if (h[t]) atomicAdd(&cnt1[t], h[t]);
    if (h[t + 256]) atomicAdd(&cnt2[t], h[t + 256]);
}

// ---------- scan 512 bucket counts -> slab bases sb[513]; zero cursors ----------
__global__ __launch_bounds__(256) void scan_buckets(const int* __restrict__ cnt,
                                                    int* __restrict__ sb,
                                                    int* __restrict__ gc) {
    __shared__ int buf[256];
    int t = threadIdx.x;
    int v = cnt[t]; buf[t] = v; __syncthreads();
    for (int o = 1; o < 256; o <<= 1) {
        int a = (t >= o) ? buf[t - o] : 0; __syncthreads();
        buf[t] += a; __syncthreads();
    }
    sb[t] = buf[t] - v;               // pass-1 region: [0, NNZ)
    __syncthreads();
    int v2 = cnt[256 + t]; buf[t] = v2; __syncthreads();
    for (int o = 1; o < 256; o <<= 1) {
        int a = (t >= o) ? buf[t - o] : 0; __syncthreads();
        buf[t] += a; __syncthreads();
    }
    sb[256 + t] = NNZ_E + buf[t] - v2;  // pass-2 region: [NNZ, 2*NNZ)
    if (t == 255) sb[512] = 2 * NNZ_E;
    gc[t] = 0; gc[256 + t] = 0;
}

// ---------- fused phase A: bin 2048 edges -> 4096 entries over 512 buckets ----------
__global__ __launch_bounds__(256) void phaseA_fused(const int* __restrict__ rows,
                                                    const int* __restrict__ cols,
                                                    const float* __restrict__ vals,
                                                    const int* __restrict__ slabBase,
                                                    int* __restrict__ gCur,
                                                    uint2* __restrict__ slab) {
    __shared__ uint2 sortedL[2 * EPB2];          // 32 KB
    __shared__ unsigned short bktL[2 * EPB2];    // 8 KB
    __shared__ int cnt[512], off[512], cur[512], gbase[512];   // 8 KB
    __shared__ int part[256];                    // 1 KB
    __shared__ int totE;
    int t = threadIdx.x;
    int base = blockIdx.x * EPB2;
    cnt[t] = 0; cnt[t + 256] = 0;
    __syncthreads();

    uint2 eA[8], eB[8];
    short bA[8], bB[8];
    #pragma unroll
    for (int j = 0; j < 8; j++) {
        int e = base + j * 256 + t;
        if (e < NNZ_E) {
            int r = rows[e], c = cols[e];
            unsigned v = __float_as_uint(vals[e]);
            int b1 = c / DPB, dl1 = c - b1 * DPB;     // pass-1 dest = col, src = row
            int b2 = r / DPB, dl2 = r - b2 * DPB;     // pass-2 dest = row, src = col
            bA[j] = (short)b1;
            eA[j].x = ((unsigned)dl1 << 18) | (unsigned)r;
            eA[j].y = v;
            bB[j] = (short)(256 + b2);
            eB[j].x = ((unsigned)dl2 << 18) | (unsigned)c;
            eB[j].y = v;
            atomicAdd(&cnt[b1], 1);
            atomicAdd(&cnt[256 + b2], 1);
        } else { bA[j] = -1; bB[j] = -1; }
    }
    __syncthreads();
    // scan 512 counts (2 per thread) -> exclusive off/cur
    int c0 = cnt[2 * t], c1 = cnt[2 * t + 1];
    int ps = c0 + c1;
    part[t] = ps; __syncthreads();
    for (int o = 1; o < 256; o <<= 1) {
        int a = (t >= o) ? part[t - o] : 0; __syncthreads();
        part[t] += a; __syncthreads();
    }
    int bs = part[t] - ps;
    off[2 * t] = bs;          cur[2 * t] = bs;
    off[2 * t + 1] = bs + c0; cur[2 * t + 1] = bs + c0;
    if (t == 255) totE = part[255];
    __syncthreads();
    // bucket-sorted scatter into LDS (both entries per edge)
    #pragma unroll
    for (int j = 0; j < 8; j++) {
        if (bA[j] >= 0) {
            int p = atomicAdd(&cur[(int)bA[j]], 1);
            sortedL[p] = eA[j]; bktL[p] = (unsigned short)bA[j];
            p = atomicAdd(&cur[(int)bB[j]], 1);
            sortedL[p] = eB[j]; bktL[p] = (unsigned short)bB[j];
        }
    }
    __syncthreads();
    // reserve global slab space, one atomic per non-empty bucket
    for (int b = t; b < 512; b += 256) {
        int n = cnt[b];
        if (n > 0) gbase[b] = atomicAdd(&gCur[b], n);
    }
    __syncthreads();
    int nE = totE;
    for (int i = t; i < nE; i += 256) {
        int b = bktL[i];
        slab[slabBase[b] + gbase[b] + (i - off[b])] = sortedL[i];
    }
}

// ---------- phase B: per-bucket exact sort + offs write + (src,val) emit ----------
__global__ __launch_bounds__(256) void phaseB(const uint2* __restrict__ slab,
                                              const int* __restrict__ slabBase,
                                              int* __restrict__ offs1,
                                              int* __restrict__ offs2,
                                              uint2* __restrict__ sorted) {
    __shared__ int cnt[DPB], sc[DPB], cur[DPB], part[256];
    int b = blockIdx.x, t = threadIdx.x;
    int sb = slabBase[b], se = slabBase[b + 1];
    int n = se - sb;
    for (int d = t; d < DPB; d += 256) cnt[d] = 0;
    __syncthreads();
    for (int i = t; i < n; i += 256)
        atomicAdd(&cnt[slab[sb + i].x >> 18], 1);
    __syncthreads();
    int d0 = t * 3;
    int c0 = (d0     < DPB) ? cnt[d0]     : 0;
    int c1 = (d0 + 1 < DPB) ? cnt[d0 + 1] : 0;
    int c2 = (d0 + 2 < DPB) ? cnt[d0 + 2] : 0;
    int ps = c0 + c1 + c2;
    part[t] = ps;
    __syncthreads();
    for (int o = 1; o < 256; o <<= 1) {
        int a = (t >= o) ? part[t - o] : 0; __syncthreads();
        part[t] += a; __syncthreads();
    }
    int bs = part[t] - ps;
    if (d0     < DPB) { sc[d0]     = bs;           cur[d0]     = bs; }
    if (d0 + 1 < DPB) { sc[d0 + 1] = bs + c0;      cur[d0 + 1] = bs + c0; }
    if (d0 + 2 < DPB) { sc[d0 + 2] = bs + c0 + c1; cur[d0 + 2] = bs + c0 + c1; }
    __syncthreads();
    int destBase = (b & 255) * DPB;
    int* offs = (b < NBUCK) ? offs1 : offs2;
    for (int d = t; d < DPB; d += 256) {
        int dd = destBase + d;
        if (dd <= N_TOTAL) offs[dd] = sb + sc[d];   // absolute index into sorted[]
    }
    for (int i = t; i < n; i += 256) {
        uint2 e = slab[sb + i];
        int dl = e.x >> 18;
        int p = atomicAdd(&cur[dl], 1);
        sorted[sb + p] = make_uint2(e.x & 0x3FFFF, e.y);
    }
}

// ---------- gather 1: SGPR metadata, saddr gathers, bf16 in/out ----------
__global__ __launch_bounds__(256) void gather1(const uint* __restrict__ srcBf,
                                               const int* __restrict__ offs,
                                               const uint2* __restrict__ edges,
                                               uint* __restrict__ dstBf) {
    int lane = threadIdx.x & 63;
    int row = blockIdx.x * 4 + (threadIdx.x >> 6);      // grid covers exactly N_TOTAL
    int row_u = __builtin_amdgcn_readfirstlane(row);
    uvec2 be;
    sload_be(be, offs + row_u);
    int beg = (int)be[0];
    int n = (int)be[1] - beg;
    const u64* ep = (const u64*)edges + beg;
    uvec16 mA, mB;
    sload_pair(mA, mB, ep);                             // <=128B past array end stays in ws
    float ax = 0.f, ay = 0.f, bx = 0.f, by = 0.f;
    chunk8(mA, n < 8 ? n : 8, lane, srcBf, ax, ay, bx, by);
    if (n > 8) {
        chunk8(mB, n - 8 < 8 ? n - 8 : 8, lane, srcBf, ax, ay, bx, by);
        if (n > 16) {
            uvec16 mC, mD;
            sload_pair(mC, mD, ep + 16);
            chunk8(mC, n - 16 < 8 ? n - 16 : 8, lane, srcBf, ax, ay, bx, by);
            if (n > 24) {
                chunk8(mD, n - 24 < 8 ? n - 24 : 8, lane, srcBf, ax, ay, bx, by);
                for (int k = 32; k < n; k++) {          // statistically never
                    uint2 e = edges[beg + k];
                    float v = __uint_as_float(e.y);
                    float2 u = unpack_bf16(srcBf[(((size_t)e.x) << 6) + lane]);
                    ax += v * u.x; ay += v * u.y;
                }
            }
        }
    }
    dstBf[(size_t)row_u * 64 + lane] = pack_bf16(ax + bx, ay + by);
}

// ---------- gather 2 + LN + residual: SGPR metadata, saddr gathers ----------
__global__ __launch_bounds__(256) void gather2_ln(const uint* __restrict__ hBf,
                                                  const int* __restrict__ offs,
                                                  const uint2* __restrict__ edges,
                                                  const uint* __restrict__ egoBf,
                                                  const float* __restrict__ gamma,
                                                  const float* __restrict__ beta,
                                                  float* __restrict__ out) {
    int lane = threadIdx.x & 63;
    int row = blockIdx.x * 4 + (threadIdx.x >> 6);
    int row_u = __builtin_amdgcn_readfirstlane(row);
    uvec2 be;
    sload_be(be, offs + row_u);
    int beg = (int)be[0];
    int n = (int)be[1] - beg;
    const u64* ep = (const u64*)edges + beg;
    uvec16 mA, mB;
    sload_pair(mA, mB, ep);
    float ax = 0.f, ay = 0.f, bx = 0.f, by = 0.f;
    chunk8(mA, n < 8 ? n : 8, lane, hBf, ax, ay, bx, by);
    if (n > 8) {
        chunk8(mB, n - 8 < 8 ? n - 8 : 8, lane, hBf, ax, ay, bx, by);
        if (n > 16) {
            uvec16 mC, mD;
            sload_pair(mC, mD, ep + 16);
            chunk8(mC, n - 16 < 8 ? n - 16 : 8, lane, hBf, ax, ay, bx, by);
            if (n > 24) {
                chunk8(mD, n - 24 < 8 ? n - 24 : 8, lane, hBf, ax, ay, bx, by);
                for (int k = 32; k < n; k++) {
                    uint2 e = edges[beg + k];
                    float v = __uint_as_float(e.y);
                    float2 u = unpack_bf16(hBf[(((size_t)e.x) << 6) + lane]);
                    ax += v * u.x; ay += v * u.y;
                }
            }
        }
    }
    float2 acc = make_float2(ax + bx, ay + by);
    float s = acc.x + acc.y;
    float sq = acc.x * acc.x + acc.y * acc.y;
    #pragma unroll
    for (int o = 1; o <= 16; o <<= 1) {
        s  += __shfl_xor(s, o, 64);
        sq += __shfl_xor(sq, o, 64);
    }
    // lanes 0 and 32 hold the two half-sums -> finish with scalar readlanes
    float sT  = rdlane_f(s, 0)  + rdlane_f(s, 32);
    float sqT = rdlane_f(sq, 0) + rdlane_f(sq, 32);
    float mu = sT * (1.0f / DIM);
    float var = sqT * (1.0f / DIM) - mu * mu;
    float rs = rsqrtf(var + 1e-5f);
    float2 g  = ((const float2*)gamma)[lane];
    float2 bb = ((const float2*)beta)[lane];
    unsigned egoW = __builtin_nontemporal_load(&egoBf[(size_t)row_u * 64 + lane]);
    float2 e2 = unpack_bf16(egoW);
    float2 o2;
    o2.x = (acc.x - mu) * rs * g.x + bb.x + e2.x;
    o2.y = (acc.y - mu) * rs * g.y + bb.y + e2.y;
    u64 ow = (u64)__float_as_uint(o2.x) | ((u64)__float_as_uint(o2.y) << 32);
    __builtin_nontemporal_store(ow, (u64*)out + (size_t)row_u * 64 + lane);
}

// ---------- fallback: atomic scatter path (ws too small) ----------
__device__ __forceinline__ void atomic_add_f32(float* p, float v) {
    __hip_atomic_fetch_add(p, v, __ATOMIC_RELAXED, __HIP_MEMORY_SCOPE_AGENT);
}
__global__ void scatter_kernel(const float* __restrict__ src, const float* __restrict__ vals,
                               const int* __restrict__ gidx, const int* __restrict__ sidx,
                               float* __restrict__ dst, int nnz) {
    int gid = blockIdx.x * blockDim.x + threadIdx.x;
    int e = gid >> 5, lane = gid & 31;
    if (e >= nnz) return;
    float v = vals[e];
    float4 x = ((const float4*)(src + (size_t)gidx[e] * DIM))[lane];
    float* d = dst + (size_t)sidx[e] * DIM + lane * 4;
    atomic_add_f32(d + 0, v * x.x); atomic_add_f32(d + 1, v * x.y);
    atomic_add_f32(d + 2, v * x.z); atomic_add_f32(d + 3, v * x.w);
}
__global__ void ln_residual_kernel(const float* __restrict__ h2, const float* __restrict__ ego,
                                   const float* __restrict__ gamma, const float* __restrict__ beta,
                                   float* __restrict__ out, int nrows) {
    int gid = blockIdx.x * blockDim.x + threadIdx.x;
    int row = gid >> 6, lane = gid & 63;
    if (row >= nrows) return;
    float2 x = ((const float2*)(h2 + (size_t)row * DIM))[lane];
    float s = x.x + x.y, sq = x.x * x.x + x.y * x.y;
    #pragma unroll
    for (int o = 32; o > 0; o >>= 1) { s += __shfl_xor(s, o, 64); sq += __shfl_xor(sq, o, 64); }
    float mu = s * (1.0f / DIM), var = sq * (1.0f / DIM) - mu * mu;
    float rs = rsqrtf(var + 1e-5f);
    float2 eg = ((const float2*)(ego + (size_t)row * DIM))[lane];
    float2 g = ((const float2*)gamma)[lane], b = ((const float2*)beta)[lane];
    float2 o2;
    o2.x = (x.x - mu) * rs * g.x + b.x + eg.x;
    o2.y = (x.y - mu) * rs * g.y + b.y + eg.y;
    ((float2*)(out + (size_t)row * DIM))[lane] = o2;
}

// ---------- launch ----------
extern "C" void kernel_launch(void* const* d_in, const int* in_sizes, int n_in,
                              void* d_out, int out_size, void* d_ws, size_t ws_size,
                              hipStream_t stream) {
    const float* ego   = (const float*)d_in[0];
    const float* vals  = (const float*)d_in[1];
    const float* gamma = (const float*)d_in[2];
    const float* beta  = (const float*)d_in[3];
    const int*   rows  = (const int*)d_in[4];
    const int*   cols  = (const int*)d_in[5];
    float* out = (float*)d_out;

    const size_t EGO_BF_B = (size_t)N_TOTAL * DIM * 2;               // 38.4 MB
    const size_t SLAB_B   = (size_t)2 * NNZ_E * sizeof(uint2);       // 24 MB
    const size_t H_BF_B   = (size_t)N_TOTAL * DIM * 2;               // 38.4 MB
    const size_t REGION_B = (SLAB_B > H_BF_B) ? SLAB_B : H_BF_B;     // hBf aliases dead slab
    const size_t SORT_B   = (size_t)2 * NNZ_E * sizeof(uint2);       // 24 MB
    const size_t OFFS_B   = ((size_t)N_TOTAL + 16) * sizeof(int);    // ~0.6 MB each
    const size_t SMALL    = 16384;
    const size_t REQ = EGO_BF_B + REGION_B + SORT_B + 2 * OFFS_B + SMALL;   // ~102 MB
    const size_t H_FP32_B = (size_t)N_TOTAL * DIM * sizeof(float);   // fallback: 76.8 MB

    char* w = (char*)d_ws;
    uint* egoBf   = (uint*)w;   w += EGO_BF_B;
    char* region  = w;          w += REGION_B;
    uint2* slab   = (uint2*)region;      // live: phaseA_fused -> phaseB
    uint* hBf     = (uint*)region;       // live: gather1 -> gather2 (slab dead by then)
    uint2* sorted = (uint2*)w;  w += SORT_B;
    int* offs1    = (int*)w;    w += OFFS_B;
    int* offs2    = (int*)w;    w += OFFS_B;
    int* cntArr   = (int*)w;    w += 512 * sizeof(int);
    int* sb       = (int*)w;    w += 516 * sizeof(int);
    int* gc       = (int*)w;    w += 512 * sizeof(int);

    if (ws_size >= REQ) {
        (void)hipMemsetAsync(cntArr, 0, 512 * sizeof(int), stream);
        conv_bf16<<<(N_TOTAL * DIM / 8) / 256, 256, 0, stream>>>(ego, egoBf);
        coarse_hist<<<512, 256, 0, stream>>>(rows, cols, cntArr, cntArr + 256);
        scan_buckets<<<1, 256, 0, stream>>>(cntArr, sb, gc);
        phaseA_fused<<<A2_BLOCKS, 256, 0, stream>>>(rows, cols, vals, sb, gc, slab);
        phaseB<<<512, 256, 0, stream>>>(slab, sb, offs1, offs2, sorted);

        int ggrid = (N_TOTAL + 3) / 4;      // 4 waves/block, 1 row/wave -> 37500
        gather1<<<ggrid, 256, 0, stream>>>(egoBf, offs1, sorted, hBf);
        gather2_ln<<<ggrid, 256, 0, stream>>>(hBf, offs2, sorted, egoBf, gamma, beta, out);
    } else {
        float* h = (float*)d_ws;            // fallback: fp32 h at ws start
        (void)hipMemsetAsync(h, 0, H_FP32_B, stream);
        (void)hipMemsetAsync(out, 0, H_FP32_B, stream);
        long total = (long)NNZ_E * 32;
        int grid = (int)((total + 255) / 256);
        scatter_kernel<<<grid, 256, 0, stream>>>(ego, vals, rows, cols, h, NNZ_E);
        scatter_kernel<<<grid, 256, 0, stream>>>(h, vals, cols, rows, out, NNZ_E);
        int lngrid = (N_TOTAL * 64 + 255) / 256;
        ln_residual_kernel<<<lngrid, 256, 0, stream>>>(out, ego, gamma, beta, out, N_TOTAL);
    }
}